// Round 15
// baseline (18384.433 us; speedup 1.0000x reference)
//
#include <hip/hip_runtime.h>

// ---------------------------------------------------------------------------
// ADRNN persistent R15 = R11 structure (global hierarchical barrier, proven)
// with 2.4x LLC-byte cut:
//  (a) retile: block = (4 gates x 128 hcols) x 16 batch -> 128 blocks;
//      each h slab now fetched 4x (was 8x) -> slab traffic 6->3MB/tick.
//  (b) rout/tout folded into r1/t1 hg0 blocks, reusing the already-staged
//      lds1 slab (r1 stages h1(k-2) = rout's input; t1 stages h3(k-5) =
//      tout's input) -> spare-wave LLC bursts (~1MB/tick) deleted.
// All mechanisms R11-proven: sc0 sc1 slab bursts + XOR-swizzled LDS,
// weights streamed from per-XCD-resident L2 slices, 8B relaxed-agent h
// stores, hierarchical monotonic-LLC barrier. No new coherence mechanisms.
// Decode: bid = rr*8 + stage*2 + hgHi (rr=hgLo*8+bg) -> XCD(bid%8) =
// stage*2+hgHi; 16 blocks/XCD; weight slice 1-2MB/XCD.
// ---------------------------------------------------------------------------

typedef _Float16 half_t;
typedef _Float16 half8 __attribute__((ext_vector_type(8)));
typedef float floatx4 __attribute__((ext_vector_type(4)));
typedef unsigned long long ull_t;

// half-unit offsets inside d_ws (identical to R11)
#define OFF_W0 0        // r_Wih0 padded  [2048][64]
#define OFF_W1 131072   // r_Whh0         [2048][512]
#define OFF_W2 1179648  // r_Wih1         [2048][512]
#define OFF_W3 2228224  // r_Whh1         [2048][512]
#define OFF_W4 3276800  // t_Wih0 cols0-48 padded [2048][64]
#define OFF_W5 3407872  // t_Wih0 cols49-95 padded [2048][64]
#define OFF_W6 3538944  // t_Whh0         [2048][512]
#define OFF_W7 4587520  // t_Wih1         [2048][512]
#define OFF_W8 5636096  // t_Whh1         [2048][512]
#define OFF_W9 6684672  // Wr padded      [48][512]
#define OFF_W10 6709248 // Wt padded      [16][512]
#define W_TOTAL 6717440
#define H_BASE  6717440              // h[4 cells][2 par][128][512] halves
#define RO_BASE 7241728              // rout16[2 par][128][64] halves
#define HALF_TOTAL 7258112
// byte offsets
#define STATE_BYTE_OFF (H_BASE * 2)          // 13434880
#define C_BYTE_OFF (HALF_TOTAL * 2)          // 14516224 (c: 4x[128][512] f32)
#define BAR_BYTE_OFF 15564800                // barrier state (4 KiB)
#define X16_BYTE_OFF (BAR_BYTE_OFF + 4096)   // optional x16 [512][128][64]
#define WS_NEED_X16 ((unsigned long long)X16_BYTE_OFF + 8388608ull)
#define STATE_BYTES (X16_BYTE_OFF - STATE_BYTE_OFF)  // h+ro+c+barrier

#define NBLK 128
#define TOUT_BASE (128 * 512 * 47)

__device__ __forceinline__ floatx4 mfma16(half8 a, half8 b, floatx4 c) {
  return __builtin_amdgcn_mfma_f32_16x16x32_f16(a, b, c, 0, 0, 0);
}
__device__ __forceinline__ float fast_sig(float x) {
  x = fminf(fmaxf(x, -30.f), 30.f);
  float e = __expf(-x);
  return __builtin_amdgcn_rcpf(1.f + e);
}
__device__ __forceinline__ float fast_tanh(float x) {
  x = fminf(fmaxf(x, -15.f), 15.f);
  float e = __expf(-2.f * x);
  return (1.f - e) * __builtin_amdgcn_rcpf(1.f + e);
}

// LLC-coherent 16B burst loads
template <int N>
__device__ __forceinline__ void burst_g(half8 (&bb)[N], const half_t* p) {
#pragma unroll
  for (int ks = 0; ks < N; ++ks)
    asm volatile("global_load_dwordx4 %0, %1, off sc0 sc1"
                 : "=v"(bb[ks]) : "v"(p + ks * 32));
}
__device__ __forceinline__ void drain_vm() {
  asm volatile("s_waitcnt vmcnt(0)" ::: "memory");
  __builtin_amdgcn_sched_barrier(0);
}
__device__ __forceinline__ void store_h4_coh(half_t* p, ull_t v) {
  __hip_atomic_store((ull_t*)p, v, __ATOMIC_RELAXED, __HIP_MEMORY_SCOPE_AGENT);
}
// poll monotonic LLC counter until >= target; PACE compile-time constant
template <int PACE>
__device__ __forceinline__ void poll_llc(const unsigned* p, unsigned target) {
  for (;;) {
    unsigned v;
    asm volatile("global_load_dword %0, %1, off sc0 sc1\ns_waitcnt vmcnt(0)"
                 : "=v"(v) : "v"(p));
    if (v >= target) return;
    __builtin_amdgcn_s_sleep(PACE);
  }
}
__device__ __forceinline__ void cnt_add(unsigned* p) {
  (void)__hip_atomic_fetch_add(p, 1u, __ATOMIC_RELAXED,
                               __HIP_MEMORY_SCOPE_AGENT);
}

// Cooperative slab staging: 16 rows x 512 halves (16KB) -> LDS, XOR-swizzled.
__device__ __forceinline__ void slab_issue(half8 (&tmp)[4],
                                           const half_t* __restrict__ src,
                                           int tid) {
#pragma unroll
  for (int j = 0; j < 4; ++j) {
    const int u = tid + j * 256;
    asm volatile("global_load_dwordx4 %0, %1, off sc0 sc1"
                 : "=v"(tmp[j]) : "v"(src + (u >> 6) * 512 + (u & 63) * 8));
  }
}
__device__ __forceinline__ void slab_write(char* base, const half8 (&tmp)[4],
                                           int tid) {
#pragma unroll
  for (int j = 0; j < 4; ++j) {
    const int u = tid + j * 256;
    const int row = u >> 6, seg = u & 63;
    *(half8*)(base + row * 1024 + ((seg * 16) ^ ((row & 7) << 4))) = tmp[j];
  }
}

// GEMM: B-frags from swizzled LDS slab, A (weights) streamed from L2.
// C/D: lane l -> col(batch)=l15, rows(gate hcols)=q*4+r.
template <int NT, int NSEG, int LDW>
__device__ __forceinline__ void gemm_lb(const half_t* __restrict__ W,
                                        const int* wrow, const char* ldsb,
                                        int lk, int q, int l15,
                                        floatx4 (&acc)[NT]) {
  const int bbase = l15 * 1024;
  const int bxor = (l15 & 7) << 4;
#pragma unroll
  for (int ks = 0; ks < NSEG; ++ks) {
    const int kb = ks * 32 + lk;
    half8 b = *(const half8*)(ldsb + bbase + ((q * 16 + ks * 64) ^ bxor));
#pragma unroll
    for (int n = 0; n < NT; ++n) {
      half8 a = *(const half8*)(W + (long)(wrow[n] + l15) * LDW + kb);
      acc[n] = mfma16(a, b, acc[n]);
    }
  }
}
// GEMM with register B-frags (RO in t0).
template <int NT, int NSEG, int LDW>
__device__ __forceinline__ void gemm_regB(const half_t* __restrict__ W,
                                          const int* wrow,
                                          const half8 (&bb)[NSEG], int lk,
                                          int l15, floatx4 (&acc)[NT]) {
#pragma unroll
  for (int ks = 0; ks < NSEG; ++ks) {
    const int kb = ks * 32 + lk;
#pragma unroll
    for (int n = 0; n < NT; ++n) {
      half8 a = *(const half8*)(W + (long)(wrow[n] + l15) * LDW + kb);
      acc[n] = mfma16(a, bb[ks], acc[n]);
    }
  }
}
// K=64 X gemm with plain cached B loads from x16.
template <int NT>
__device__ __forceinline__ void gemm_x16(const half_t* __restrict__ W,
                                         const int* wrow,
                                         const half_t* __restrict__ xb, int lk,
                                         int l15, floatx4 (&acc)[NT]) {
#pragma unroll
  for (int ks = 0; ks < 2; ++ks) {
    const int kb = ks * 32 + lk;
    half8 b = *(const half8*)(xb + kb);
#pragma unroll
    for (int n = 0; n < NT; ++n) {
      half8 a = *(const half8*)(W + (long)(wrow[n] + l15) * 64 + kb);
      acc[n] = mfma16(a, b, acc[n]);
    }
  }
}
// Fallback X gemm from fp32 inputs.
template <int NT>
__device__ __forceinline__ void gemm_xf(const float* __restrict__ xr,
                                        const float* __restrict__ xt, int t,
                                        int batch, const half_t* __restrict__ W,
                                        const int* wrow, int lk, int l15,
                                        floatx4 (&acc)[NT]) {
#pragma unroll
  for (int ks = 0; ks < 2; ++ks) {
    const int kb = ks * 32 + lk;
    half8 b;
    const long base = (long)batch * 512 + t;
#pragma unroll
    for (int j = 0; j < 8; ++j) {
      const int kk = kb + j;
      float f = 0.f;
      if (kk < 47) f = xr[base * 47 + kk];
      else if (kk < 49) f = xt[base * 2 + (kk - 47)];
      b[j] = (half_t)f;
    }
#pragma unroll
    for (int n = 0; n < NT; ++n) {
      half8 a = *(const half8*)(W + (long)(wrow[n] + l15) * 64 + kb);
      acc[n] = mfma16(a, b, acc[n]);
    }
  }
}

// LSTM epilogue, 2 hcol-groups: acc[n], n=g*2+j (gate g, group j).
// Lane owns batch row `batch`, h-cols c0w + j*16 + q*4 .. +3.
__device__ __forceinline__ void lstm_epi2(floatx4 (&acc)[8],
                                          const float* __restrict__ bias,
                                          float* __restrict__ cst,
                                          half_t* __restrict__ hdst,
                                          int batch, int c0w, int q) {
#pragma unroll
  for (int j = 0; j < 2; ++j) {
    const int hcol0 = c0w + j * 16 + q * 4;
    const floatx4 bI = *(const floatx4*)(bias + hcol0);
    const floatx4 bF = *(const floatx4*)(bias + 512 + hcol0);
    const floatx4 bG = *(const floatx4*)(bias + 1024 + hcol0);
    const floatx4 bO = *(const floatx4*)(bias + 1536 + hcol0);
    const int off = batch * 512 + hcol0;
    floatx4 cold = *(floatx4*)(cst + off);
    floatx4 cn;
    union { ull_t u; _Float16 h[4]; } pk;
#pragma unroll
    for (int r = 0; r < 4; ++r) {
      const float gi = acc[0 + j][r] + bI[r];
      const float gf = acc[2 + j][r] + bF[r];
      const float gg = acc[4 + j][r] + bG[r];
      const float go = acc[6 + j][r] + bO[r];
      cn[r] = fast_sig(gf) * cold[r] + fast_sig(gi) * fast_tanh(gg);
      pk.h[r] = (half_t)(fast_sig(go) * fast_tanh(cn[r]));
    }
    *(floatx4*)(cst + off) = cn;
    store_h4_coh(hdst + off, pk.u);
  }
}

__global__ __launch_bounds__(256, 1) void adrnn_persist(
    const float* __restrict__ xr, const float* __restrict__ xt,
    const float* __restrict__ b_r0, const float* __restrict__ b_r1,
    const float* __restrict__ b_t0, const float* __restrict__ b_t1,
    const float* __restrict__ brv, const float* __restrict__ btv,
    half_t* __restrict__ w16, float* __restrict__ cbase,
    float* __restrict__ out, unsigned* bar, const half_t* __restrict__ x16,
    int use_x16) {
  __shared__ half8 lds_v[2048];  // 32KB: two 16KB swizzled B slabs
  char* lds0 = (char*)lds_v;
  char* lds1 = lds0 + 16384;

  const int bid = blockIdx.x;
  const int tid = threadIdx.x;
  const int lane = tid & 63;
  const int w = tid >> 6;
  const int l15 = lane & 15;
  const int q = lane >> 4;
  const int lk = q * 8;
  half_t* H = w16 + H_BASE;
  half_t* RO = w16 + RO_BASE;
#define HB(cell, p) (H + (((cell)*2 + (p)) << 16))

  // decode: bid = (hgLo*8 + bg)*8 + stage*2 + hgHi  -> XCD = stage*2+hgHi
  const int stage = (bid & 7) >> 1;
  const int hgHi = bid & 1;
  const int rr = bid >> 3;        // 0..15
  const int hgLo = rr >> 3;       // 0..1
  const int bg = rr & 7;          // 0..7
  const int hg = hgHi * 2 + hgLo; // 0..3 (128 hcols each)
  const int c0w = hg * 128 + w * 32;   // wave covers 32 hcols
  const int b0 = bg * 16;
  const int batch = b0 + l15;
  const int sd = (stage == 0) ? 0 : (stage == 1) ? 1 : (stage == 2) ? 3 : 4;
  // wrow[n], n = g*2 + j: gate g, hcol group j (16 cols each)
  int wrow[8];
#pragma unroll
  for (int g = 0; g < 4; ++g) {
    wrow[g * 2 + 0] = g * 512 + c0w;
    wrow[g * 2 + 1] = g * 512 + c0w + 16;
  }
  const bool do_rout = (stage == 1 && hg == 0 && w < 3);
  const bool do_tout = (stage == 3 && hg == 0 && w == 0);

  // hierarchical barrier lines (monotonic LLC); 16 blocks/XCD, 8 leaders
  unsigned* larr = bar + (bid & 7) * 32;
  unsigned* garr = bar + 256;
  unsigned* lgen = bar + 288 + (bid & 7) * 32;

  for (int k = 0; k < 517; ++k) {
    const int par = k & 1, pq = par ^ 1;
    const int t = k - sd;
    const bool valid = (t >= 0 && t < 512);

    // ---- cooperative LDS staging of B slabs (16 rows x 1KB each) ----
    {
      half8 s0[4], s1[4];
      if (stage == 0) {
        slab_issue(s0, HB(0, pq) + b0 * 512, tid);
        drain_vm();
        slab_write(lds0, s0, tid);
      } else if (stage == 1) {
        slab_issue(s0, HB(0, pq) + b0 * 512, tid);
        slab_issue(s1, HB(1, pq) + b0 * 512, tid);
        drain_vm();
        slab_write(lds0, s0, tid);
        slab_write(lds1, s1, tid);
      } else if (stage == 2) {
        slab_issue(s0, HB(2, pq) + b0 * 512, tid);
        drain_vm();
        slab_write(lds0, s0, tid);
      } else {
        slab_issue(s0, HB(2, pq) + b0 * 512, tid);
        slab_issue(s1, HB(3, pq) + b0 * 512, tid);
        drain_vm();
        slab_write(lds0, s0, tid);
        slab_write(lds1, s1, tid);
      }
    }
    __syncthreads();

    // ---- main compute ----
    if (valid) {
      floatx4 acc[8] = {};
      if (stage == 0) {        // r0: X @ Wih0^T + h0 @ Whh0^T
        if (use_x16)
          gemm_x16<8>(w16 + OFF_W0, wrow, x16 + (long)t * 8192 + batch * 64, lk, l15, acc);
        else
          gemm_xf<8>(xr, xt, t, batch, w16 + OFF_W0, wrow, lk, l15, acc);
        gemm_lb<8, 16, 512>(w16 + OFF_W1, wrow, lds0, lk, q, l15, acc);
        lstm_epi2(acc, b_r0, cbase + 0 * 65536, HB(0, par), batch, c0w, q);
      } else if (stage == 1) { // r1
        gemm_lb<8, 16, 512>(w16 + OFF_W2, wrow, lds0, lk, q, l15, acc);
        gemm_lb<8, 16, 512>(w16 + OFF_W3, wrow, lds1, lk, q, l15, acc);
        lstm_epi2(acc, b_r1, cbase + 1 * 65536, HB(1, par), batch, c0w, q);
      } else if (stage == 2) { // t0: X + RO + h2
        half8 bro[2];
        burst_g<2>(bro, RO + pq * 8192 + batch * 64 + lk);
        drain_vm();
        if (use_x16)
          gemm_x16<8>(w16 + OFF_W4, wrow, x16 + (long)t * 8192 + batch * 64, lk, l15, acc);
        else
          gemm_xf<8>(xr, xt, t, batch, w16 + OFF_W4, wrow, lk, l15, acc);
        gemm_regB<8, 2, 64>(w16 + OFF_W5, wrow, bro, lk, l15, acc);
        gemm_lb<8, 16, 512>(w16 + OFF_W6, wrow, lds0, lk, q, l15, acc);
        lstm_epi2(acc, b_t0, cbase + 2 * 65536, HB(2, par), batch, c0w, q);
      } else {                 // t1
        gemm_lb<8, 16, 512>(w16 + OFF_W7, wrow, lds0, lk, q, l15, acc);
        gemm_lb<8, 16, 512>(w16 + OFF_W8, wrow, lds1, lk, q, l15, acc);
        lstm_epi2(acc, b_t1, cbase + 3 * 65536, HB(3, par), batch, c0w, q);
      }
    }

    // ---- rout folded into r1-hg0 blocks: lds1 = h1(t=k-2) slab ----
    if (do_rout) {
      const int tro = k - 2;
      if (tro >= 0 && tro < 512) {
        int wr1[1] = {w * 16};
        floatx4 accr[1] = {};
        gemm_lb<1, 16, 512>(w16 + OFF_W9, wr1, lds1, lk, q, l15, accr);
        const int rb = b0 + l15;
        const int wc0 = w * 16 + q * 4;
        union { ull_t u2; _Float16 h[4]; } rp;
#pragma unroll
        for (int r = 0; r < 4; ++r) {
          const int wc = wc0 + r;
          float v = 0.f;
          if (wc < 47) {
            v = accr[0][r] + brv[wc];
            out[((long)rb * 512 + tro) * 47 + wc] = v;
          }
          rp.h[r] = (half_t)v;
        }
        store_h4_coh(RO + par * 8192 + rb * 64 + wc0, rp.u2);
      }
    }
    // ---- tout folded into t1-hg0 blocks: lds1 = h3(t=k-5) slab ----
    if (do_tout) {
      const int tto = k - 5;
      if (tto >= 0 && tto < 512) {
        int wt1[1] = {0};
        floatx4 accw[1] = {};
        gemm_lb<1, 16, 512>(w16 + OFF_W10, wt1, lds1, lk, q, l15, accw);
        if (q == 0) {
          const int rb = b0 + l15;
#pragma unroll
          for (int r = 0; r < 2; ++r)
            out[TOUT_BASE + ((long)rb * 512 + tto) * 2 + r] = accw[0][r] + btv[r];
        }
      }
    }

    // ---- hierarchical barrier (monotonic LLC counters; R8/R11-proven) ----
    asm volatile("s_waitcnt vmcnt(0)" ::: "memory");
    __syncthreads();
    if (tid == 0) {
      const unsigned ku = (unsigned)k + 1u;
      cnt_add(larr);
      if (bid < 8) {
        poll_llc<1>(larr, 16u * ku);   // 16 blocks per XCD
        cnt_add(garr);
        poll_llc<1>(garr, 8u * ku);    // 8 leaders
        cnt_add(lgen);
      } else {
        poll_llc<3>(lgen, ku);
      }
    }
    __syncthreads();
    asm volatile("" ::: "memory");
  }
#undef HB
}

// fp32 -> fp16 weight conversion into [n][k] layout with zero padding.
__global__ __launch_bounds__(256) void conv_w(
    const float* __restrict__ rWih0, const float* __restrict__ rWhh0,
    const float* __restrict__ rWih1, const float* __restrict__ rWhh1,
    const float* __restrict__ tWih0, const float* __restrict__ tWhh0,
    const float* __restrict__ tWih1, const float* __restrict__ tWhh1,
    const float* __restrict__ Wr, const float* __restrict__ Wt,
    half_t* __restrict__ w16) {
  const int idx = blockIdx.x * 256 + threadIdx.x;
  if (idx >= W_TOTAL) return;
  float v = 0.f;
  if (idx < OFF_W1) {
    int n = idx >> 6, kk = idx & 63;
    if (kk < 49) v = rWih0[n * 49 + kk];
  } else if (idx < OFF_W2) {
    int r = idx - OFF_W1; v = rWhh0[r];
  } else if (idx < OFF_W3) {
    int r = idx - OFF_W2; v = rWih1[r];
  } else if (idx < OFF_W4) {
    int r = idx - OFF_W3; v = rWhh1[r];
  } else if (idx < OFF_W5) {
    int r = idx - OFF_W4; int n = r >> 6, kk = r & 63;
    if (kk < 49) v = tWih0[n * 96 + kk];
  } else if (idx < OFF_W6) {
    int r = idx - OFF_W5; int n = r >> 6, kk = r & 63;
    if (kk < 47) v = tWih0[n * 96 + 49 + kk];
  } else if (idx < OFF_W7) {
    int r = idx - OFF_W6; v = tWhh0[r];
  } else if (idx < OFF_W8) {
    int r = idx - OFF_W7; v = tWih1[r];
  } else if (idx < OFF_W9) {
    int r = idx - OFF_W8; v = tWhh1[r];
  } else if (idx < OFF_W10) {
    int r = idx - OFF_W9; int n = r >> 9, kk = r & 511;
    if (n < 47) v = Wr[n * 512 + kk];
  } else {
    int r = idx - OFF_W10; int n = r >> 9, kk = r & 511;
    if (n < 2) v = Wt[n * 512 + kk];
  }
  w16[idx] = (half_t)v;
}

// fp32 x_r/x_t -> fp16 [t][128][64] (cols 0..46 = x_r, 47..48 = x_t, rest 0)
__global__ __launch_bounds__(256) void conv_x(const float* __restrict__ xr,
                                              const float* __restrict__ xt,
                                              half_t* __restrict__ x16) {
  const int idx = blockIdx.x * 256 + threadIdx.x;
  if (idx >= 512 * 128 * 64) return;
  const int kk = idx & 63;
  const int row = (idx >> 6) & 127;
  const int t = idx >> 13;
  float v = 0.f;
  if (kk < 47) v = xr[(row * 512 + t) * 47 + kk];
  else if (kk < 49) v = xt[(row * 512 + t) * 2 + (kk - 47)];
  x16[idx] = (half_t)v;
}

extern "C" void kernel_launch(void* const* d_in, const int* in_sizes, int n_in,
                              void* d_out, int out_size, void* d_ws,
                              size_t ws_size, hipStream_t stream) {
  const float* xr = (const float*)d_in[0];
  const float* xt = (const float*)d_in[1];
  const float* rWih0 = (const float*)d_in[2];
  const float* rWhh0 = (const float*)d_in[3];
  const float* r_b0 = (const float*)d_in[4];
  const float* rWih1 = (const float*)d_in[5];
  const float* rWhh1 = (const float*)d_in[6];
  const float* r_b1 = (const float*)d_in[7];
  const float* tWih0 = (const float*)d_in[8];
  const float* tWhh0 = (const float*)d_in[9];
  const float* t_b0 = (const float*)d_in[10];
  const float* tWih1 = (const float*)d_in[11];
  const float* tWhh1 = (const float*)d_in[12];
  const float* t_b1 = (const float*)d_in[13];
  const float* Wr = (const float*)d_in[14];
  const float* br = (const float*)d_in[15];
  const float* Wt = (const float*)d_in[16];
  const float* bt = (const float*)d_in[17];

  half_t* w16 = (half_t*)d_ws;
  float* cbase = (float*)((char*)d_ws + C_BYTE_OFF);
  unsigned* bar = (unsigned*)((char*)d_ws + BAR_BYTE_OFF);
  half_t* x16 = (half_t*)((char*)d_ws + X16_BYTE_OFF);
  float* out = (float*)d_out;
  int use_x16 = (ws_size >= WS_NEED_X16) ? 1 : 0;

  // zero h / ro / c / barrier state every call (deterministic)
  (void)hipMemsetAsync((char*)d_ws + STATE_BYTE_OFF, 0, STATE_BYTES, stream);

  conv_w<<<(W_TOTAL + 255) / 256, 256, 0, stream>>>(
      rWih0, rWhh0, rWih1, rWhh1, tWih0, tWhh0, tWih1, tWhh1, Wr, Wt, w16);
  if (use_x16)
    conv_x<<<(512 * 128 * 64) / 256, 256, 0, stream>>>(xr, xt, x16);

  adrnn_persist<<<NBLK, 256, 0, stream>>>(xr, xt, r_b0, r_b1, t_b0, t_b1, br,
                                          bt, w16, cbase, out, bar, x16,
                                          use_x16);
}

// Round 16
// 9246.044 us; speedup vs baseline: 1.9884x; 1.9884x over previous
//
#include <hip/hip_runtime.h>

// ---------------------------------------------------------------------------
// ADRNN persistent R16 = R11 (proven 9.2ms) + c-state in REGISTERS.
// Each block owns a fixed (hg,bg) tile across all ticks; each thread owns
// exactly one floatx4 of c (4 hcols x 1 batch row) -> c lives in a register
// across the 517-tick loop, deleting ~2MB/tick of L2/HBM c traffic (the
// dominant share of R11's 2.18MB/tick @ ~120GB/s effective = 18us ticks).
// Everything else byte-identical to R11: 256 blocks x 256 threads, decode
// bid=((hg&3)*8+bg)*8+stage*2+(hg>>2) (weights L2-resident per XCD), LDS
// slab staging + XOR swizzle, sc0 sc1 h bursts, 8B relaxed-agent h stores,
// spare-wave rout/tout, hierarchical monotonic-LLC barrier.
// ---------------------------------------------------------------------------

typedef _Float16 half_t;
typedef _Float16 half8 __attribute__((ext_vector_type(8)));
typedef float floatx4 __attribute__((ext_vector_type(4)));
typedef unsigned long long ull_t;

// half-unit offsets inside d_ws
#define OFF_W0 0        // r_Wih0 padded  [2048][64]
#define OFF_W1 131072   // r_Whh0         [2048][512]
#define OFF_W2 1179648  // r_Wih1         [2048][512]
#define OFF_W3 2228224  // r_Whh1         [2048][512]
#define OFF_W4 3276800  // t_Wih0 cols0-48 padded [2048][64]
#define OFF_W5 3407872  // t_Wih0 cols49-95 padded [2048][64]
#define OFF_W6 3538944  // t_Whh0         [2048][512]
#define OFF_W7 4587520  // t_Wih1         [2048][512]
#define OFF_W8 5636096  // t_Whh1         [2048][512]
#define OFF_W9 6684672  // Wr padded      [48][512]
#define OFF_W10 6709248 // Wt padded      [16][512]
#define W_TOTAL 6717440
#define H_BASE  6717440              // h[4 cells][2 par][128][512] halves
#define RO_BASE 7241728              // rout16[2 par][128][64] halves
#define HALF_TOTAL 7258112
// byte offsets
#define STATE_BYTE_OFF (H_BASE * 2)          // 13434880
#define C_BYTE_OFF (HALF_TOTAL * 2)          // 14516224 (unused now)
#define BAR_BYTE_OFF 15564800                // barrier state (4 KiB)
#define X16_BYTE_OFF (BAR_BYTE_OFF + 4096)   // optional x16 [512][128][64]
#define WS_NEED_X16 ((unsigned long long)X16_BYTE_OFF + 8388608ull)
#define STATE_BYTES (X16_BYTE_OFF - STATE_BYTE_OFF)  // h+ro+c+barrier

#define NBLK 256
#define TOUT_BASE (128 * 512 * 47)

__device__ __forceinline__ floatx4 mfma16(half8 a, half8 b, floatx4 c) {
  return __builtin_amdgcn_mfma_f32_16x16x32_f16(a, b, c, 0, 0, 0);
}
__device__ __forceinline__ float fast_sig(float x) {
  x = fminf(fmaxf(x, -30.f), 30.f);
  float e = __expf(-x);
  return __builtin_amdgcn_rcpf(1.f + e);
}
__device__ __forceinline__ float fast_tanh(float x) {
  x = fminf(fmaxf(x, -15.f), 15.f);
  float e = __expf(-2.f * x);
  return (1.f - e) * __builtin_amdgcn_rcpf(1.f + e);
}

// LLC-coherent 16B burst loads
template <int N>
__device__ __forceinline__ void coh_stage(half8 (&bb)[N], const half_t* p) {
#pragma unroll
  for (int ks = 0; ks < N; ++ks)
    asm volatile("global_load_dwordx4 %0, %1, off sc0 sc1"
                 : "=v"(bb[ks]) : "v"(p + ks * 32));
}
__device__ __forceinline__ void drain_vm() {
  asm volatile("s_waitcnt vmcnt(0)" ::: "memory");
  __builtin_amdgcn_sched_barrier(0);
}
__device__ __forceinline__ void store_h4_coh(half_t* p, half_t h0, half_t h1,
                                             half_t h2, half_t h3) {
  union { ull_t u; _Float16 h[4]; } x;
  x.h[0] = h0; x.h[1] = h1; x.h[2] = h2; x.h[3] = h3;
  __hip_atomic_store((ull_t*)p, x.u, __ATOMIC_RELAXED,
                     __HIP_MEMORY_SCOPE_AGENT);
}
// poll monotonic LLC counter until >= target; PACE is compile-time constant
template <int PACE>
__device__ __forceinline__ void poll_llc(const unsigned* p, unsigned target) {
  for (;;) {
    unsigned v;
    asm volatile("global_load_dword %0, %1, off sc0 sc1\ns_waitcnt vmcnt(0)"
                 : "=v"(v) : "v"(p));
    if (v >= target) return;
    __builtin_amdgcn_s_sleep(PACE);
  }
}

// Cooperative slab staging: 16 rows x 512 halves (16KB) -> LDS, XOR-swizzled.
__device__ __forceinline__ void slab_issue(half8 (&tmp)[4],
                                           const half_t* __restrict__ src,
                                           int tid) {
#pragma unroll
  for (int j = 0; j < 4; ++j) {
    const int u = tid + j * 256;
    asm volatile("global_load_dwordx4 %0, %1, off sc0 sc1"
                 : "=v"(tmp[j]) : "v"(src + (u >> 6) * 512 + (u & 63) * 8));
  }
}
__device__ __forceinline__ void slab_write(char* base, const half8 (&tmp)[4],
                                           int tid) {
#pragma unroll
  for (int j = 0; j < 4; ++j) {
    const int u = tid + j * 256;
    const int row = u >> 6, seg = u & 63;
    *(half8*)(base + row * 1024 + ((seg * 16) ^ ((row & 7) << 4))) = tmp[j];
  }
}

// GEMM: B-frags from swizzled LDS slab, A (weights) streamed from L2.
// C/D: lane l -> col(batch)=l15, rows(gate hcols)=q*4+r.
template <int NT, int NSEG, int LDW>
__device__ __forceinline__ void gemm_lb(const half_t* __restrict__ W,
                                        const int* wrow, const char* ldsb,
                                        int lk, int q, int l15,
                                        floatx4 (&acc)[NT]) {
  const int bbase = l15 * 1024;
  const int bxor = (l15 & 7) << 4;
#pragma unroll
  for (int ks = 0; ks < NSEG; ++ks) {
    const int kb = ks * 32 + lk;
    half8 b = *(const half8*)(ldsb + bbase + ((q * 16 + ks * 64) ^ bxor));
#pragma unroll
    for (int n = 0; n < NT; ++n) {
      half8 a = *(const half8*)(W + (long)(wrow[n] + l15) * LDW + kb);
      acc[n] = mfma16(a, b, acc[n]);
    }
  }
}

// GEMM with register B-frags (RO, spare rout/tout).
template <int NT, int NSEG, int LDW>
__device__ __forceinline__ void gemm_regB(const half_t* __restrict__ W,
                                          const int* wrow,
                                          const half8 (&bb)[NSEG], int lk,
                                          int l15, floatx4 (&acc)[NT]) {
#pragma unroll
  for (int ks = 0; ks < NSEG; ++ks) {
    const int kb = ks * 32 + lk;
#pragma unroll
    for (int n = 0; n < NT; ++n) {
      half8 a = *(const half8*)(W + (long)(wrow[n] + l15) * LDW + kb);
      acc[n] = mfma16(a, bb[ks], acc[n]);
    }
  }
}

// K=64 X gemm with plain cached B loads from x16.
__device__ __forceinline__ void gemm_x16(const half_t* __restrict__ W,
                                         const int* wrow,
                                         const half_t* __restrict__ xb, int lk,
                                         int l15, floatx4 (&acc)[4]) {
#pragma unroll
  for (int ks = 0; ks < 2; ++ks) {
    const int kb = ks * 32 + lk;
    half8 b = *(const half8*)(xb + kb);
#pragma unroll
    for (int n = 0; n < 4; ++n) {
      half8 a = *(const half8*)(W + (long)(wrow[n] + l15) * 64 + kb);
      acc[n] = mfma16(a, b, acc[n]);
    }
  }
}
// Fallback X gemm from fp32 inputs.
__device__ __forceinline__ void gemm_xf(const float* __restrict__ xr,
                                        const float* __restrict__ xt, int t,
                                        int batch, const half_t* __restrict__ W,
                                        const int* wrow, int lk, int l15,
                                        floatx4 (&acc)[4]) {
#pragma unroll
  for (int ks = 0; ks < 2; ++ks) {
    const int kb = ks * 32 + lk;
    half8 b;
    const long base = (long)batch * 512 + t;
#pragma unroll
    for (int j = 0; j < 8; ++j) {
      const int kk = kb + j;
      float f = 0.f;
      if (kk < 47) f = xr[base * 47 + kk];
      else if (kk < 49) f = xt[base * 2 + (kk - 47)];
      b[j] = (half_t)f;
    }
#pragma unroll
    for (int n = 0; n < 4; ++n) {
      half8 a = *(const half8*)(W + (long)(wrow[n] + l15) * 64 + kb);
      acc[n] = mfma16(a, b, acc[n]);
    }
  }
}

// LSTM epilogue with REGISTER c-state: creg is the thread's persistent c.
__device__ __forceinline__ void lstm_epi_reg(floatx4 (&acc)[4],
                                             const float* __restrict__ bias,
                                             floatx4& creg,
                                             half_t* __restrict__ hdst,
                                             int batch, int hcol0) {
  const floatx4 bI = *(const floatx4*)(bias + hcol0);
  const floatx4 bF = *(const floatx4*)(bias + 512 + hcol0);
  const floatx4 bG = *(const floatx4*)(bias + 1024 + hcol0);
  const floatx4 bO = *(const floatx4*)(bias + 1536 + hcol0);
  const int off = batch * 512 + hcol0;
  half_t hn[4];
#pragma unroll
  for (int r = 0; r < 4; ++r) {
    const float gi = acc[0][r] + bI[r];
    const float gf = acc[1][r] + bF[r];
    const float gg = acc[2][r] + bG[r];
    const float go = acc[3][r] + bO[r];
    creg[r] = fast_sig(gf) * creg[r] + fast_sig(gi) * fast_tanh(gg);
    hn[r] = (half_t)(fast_sig(go) * fast_tanh(creg[r]));
  }
  store_h4_coh(hdst + off, hn[0], hn[1], hn[2], hn[3]);
}

__global__ __launch_bounds__(256, 1) void adrnn_persist(
    const float* __restrict__ xr, const float* __restrict__ xt,
    const float* __restrict__ b_r0, const float* __restrict__ b_r1,
    const float* __restrict__ b_t0, const float* __restrict__ b_t1,
    const float* __restrict__ brv, const float* __restrict__ btv,
    half_t* __restrict__ w16, float* __restrict__ cbase,
    float* __restrict__ out, unsigned* bar, const half_t* __restrict__ x16,
    int use_x16) {
  __shared__ half8 lds_v[2048];  // 32KB: two 16KB swizzled B slabs
  char* lds0 = (char*)lds_v;
  char* lds1 = lds0 + 16384;

  const int bid = blockIdx.x;
  const int tid = threadIdx.x;
  const int lane = tid & 63;
  const int w = tid >> 6;
  const int l15 = lane & 15;
  const int q = lane >> 4;
  const int lk = q * 8;
  half_t* H = w16 + H_BASE;
  half_t* RO = w16 + RO_BASE;
#define HB(cell, p) (H + (((cell)*2 + (p)) << 16))

  // decode: bid = ((hg&3)*8 + bg)*8 + stage*2 + (hg>>2)
  const int stage = (bid & 7) >> 1;
  const int hgHi = bid & 1;
  const int rr = bid >> 3;        // 0..31
  const int hgLo = rr >> 3;       // 0..3
  const int bg = rr & 7;          // 0..7
  const int hg = hgHi * 4 + hgLo; // 0..7 (64 hcols each)
  const int c0w = hg * 64 + w * 16;
  const int b0 = bg * 16;
  const int batch = b0 + l15;
  const int hcol0 = c0w + q * 4;
  const int sd = (stage == 0) ? 0 : (stage == 1) ? 1 : (stage == 2) ? 3 : 4;
  int wrow[4] = {c0w, 512 + c0w, 1024 + c0w, 1536 + c0w};
  // spares: stage-0 blocks with hg<2; 64 waves, first 32 used
  const int flat = (hg * 8 + bg) * 4 + w;
  const bool is_spare = (stage == 0 && hg < 2 && flat < 32);

  // hierarchical barrier lines (monotonic LLC)
  unsigned* larr = bar + (bid & 7) * 32;
  unsigned* garr = bar + 256;
  unsigned* lgen = bar + 288 + (bid & 7) * 32;

  floatx4 creg = {0.f, 0.f, 0.f, 0.f};  // persistent register c-state

  for (int k = 0; k < 517; ++k) {
    const int par = k & 1, pq = par ^ 1;
    const int t = k - sd;
    const bool valid = (t >= 0 && t < 512);

    // ---- cooperative LDS staging of B slabs (16 rows x 1KB each) ----
    if (valid) {
      half8 s0[4], s1[4];
      if (stage == 0) {
        slab_issue(s0, HB(0, pq) + b0 * 512, tid);
        drain_vm();
        slab_write(lds0, s0, tid);
      } else if (stage == 1) {
        slab_issue(s0, HB(0, pq) + b0 * 512, tid);
        slab_issue(s1, HB(1, pq) + b0 * 512, tid);
        drain_vm();
        slab_write(lds0, s0, tid);
        slab_write(lds1, s1, tid);
      } else if (stage == 2) {
        slab_issue(s0, HB(2, pq) + b0 * 512, tid);
        drain_vm();
        slab_write(lds0, s0, tid);
      } else {
        slab_issue(s0, HB(2, pq) + b0 * 512, tid);
        slab_issue(s1, HB(3, pq) + b0 * 512, tid);
        drain_vm();
        slab_write(lds0, s0, tid);
        slab_write(lds1, s1, tid);
      }
    }
    __syncthreads();

    // ---- main compute ----
    if (valid) {
      floatx4 acc[4] = {};
      if (stage == 0) {        // r0: X @ Wih0^T + h0 @ Whh0^T
        if (use_x16)
          gemm_x16(w16 + OFF_W0, wrow, x16 + (long)t * 8192 + batch * 64, lk, l15, acc);
        else
          gemm_xf(xr, xt, t, batch, w16 + OFF_W0, wrow, lk, l15, acc);
        gemm_lb<4, 16, 512>(w16 + OFF_W1, wrow, lds0, lk, q, l15, acc);
        lstm_epi_reg(acc, b_r0, creg, HB(0, par), batch, hcol0);
      } else if (stage == 1) { // r1
        gemm_lb<4, 16, 512>(w16 + OFF_W2, wrow, lds0, lk, q, l15, acc);
        gemm_lb<4, 16, 512>(w16 + OFF_W3, wrow, lds1, lk, q, l15, acc);
        lstm_epi_reg(acc, b_r1, creg, HB(1, par), batch, hcol0);
      } else if (stage == 2) { // t0: X + RO + h2
        half8 bro[2];
        coh_stage<2>(bro, RO + pq * 8192 + batch * 64 + lk);
        drain_vm();
        if (use_x16)
          gemm_x16(w16 + OFF_W4, wrow, x16 + (long)t * 8192 + batch * 64, lk, l15, acc);
        else
          gemm_xf(xr, xt, t, batch, w16 + OFF_W4, wrow, lk, l15, acc);
        gemm_regB<4, 2, 64>(w16 + OFF_W5, wrow, bro, lk, l15, acc);
        gemm_lb<4, 16, 512>(w16 + OFF_W6, wrow, lds0, lk, q, l15, acc);
        lstm_epi_reg(acc, b_t0, creg, HB(2, par), batch, hcol0);
      } else {                 // t1
        gemm_lb<4, 16, 512>(w16 + OFF_W7, wrow, lds0, lk, q, l15, acc);
        gemm_lb<4, 16, 512>(w16 + OFF_W8, wrow, lds1, lk, q, l15, acc);
        lstm_epi_reg(acc, b_t1, creg, HB(3, par), batch, hcol0);
      }
    }

    // ---- rout/tout on stage-0 spare waves ----
    if (is_spare) {
      if (flat < 24) {  // rout: 3 n-tiles x 8 batch-tiles, t = k-2
        const int tr = k - 2;
        if (tr >= 0 && tr < 512) {
          const int n = flat >> 3, btl = flat & 7;
          const int rb = btl * 16 + l15;
          half8 bs[16];
          coh_stage<16>(bs, HB(1, pq) + rb * 512 + lk);
          drain_vm();
          int wr1[1] = {n * 16};
          floatx4 accr[1] = {};
          gemm_regB<1, 16, 512>(w16 + OFF_W9, wr1, bs, lk, l15, accr);
          const int wc0 = n * 16 + q * 4;
          half_t ro4[4];
#pragma unroll
          for (int r = 0; r < 4; ++r) {
            const int wc = wc0 + r;
            float v = 0.f;
            if (wc < 47) {
              v = accr[0][r] + brv[wc];
              out[((long)rb * 512 + tr) * 47 + wc] = v;
            }
            ro4[r] = (half_t)v;
          }
          store_h4_coh(RO + par * 8192 + rb * 64 + wc0, ro4[0], ro4[1], ro4[2], ro4[3]);
        }
      } else {          // tout: 8 batch-tiles, t = k-5
        const int tt = k - 5;
        if (tt >= 0 && tt < 512) {
          const int btl = flat - 24;
          const int rb = btl * 16 + l15;
          half8 bs[16];
          coh_stage<16>(bs, HB(3, pq) + rb * 512 + lk);
          drain_vm();
          int wt1[1] = {0};
          floatx4 accw[1] = {};
          gemm_regB<1, 16, 512>(w16 + OFF_W10, wt1, bs, lk, l15, accw);
          if (q == 0) {
#pragma unroll
            for (int r = 0; r < 2; ++r)
              out[TOUT_BASE + ((long)rb * 512 + tt) * 2 + r] = accw[0][r] + btv[r];
          }
        }
      }
    }

    // ---- hierarchical barrier (monotonic LLC counters; R8/R11-proven) ----
    asm volatile("s_waitcnt vmcnt(0)" ::: "memory");
    __syncthreads();
    if (tid == 0) {
      const unsigned ku = (unsigned)k + 1u;
      (void)__hip_atomic_fetch_add(larr, 1u, __ATOMIC_RELAXED,
                                   __HIP_MEMORY_SCOPE_AGENT);
      if (bid < 8) {
        poll_llc<1>(larr, 32u * ku);
        (void)__hip_atomic_fetch_add(garr, 1u, __ATOMIC_RELAXED,
                                     __HIP_MEMORY_SCOPE_AGENT);
        poll_llc<1>(garr, 8u * ku);
        (void)__hip_atomic_fetch_add(lgen, 1u, __ATOMIC_RELAXED,
                                     __HIP_MEMORY_SCOPE_AGENT);
      } else {
        poll_llc<3>(lgen, ku);
      }
    }
    __syncthreads();
    asm volatile("" ::: "memory");
  }
#undef HB
}

// fp32 -> fp16 weight conversion into [n][k] layout with zero padding.
__global__ __launch_bounds__(256) void conv_w(
    const float* __restrict__ rWih0, const float* __restrict__ rWhh0,
    const float* __restrict__ rWih1, const float* __restrict__ rWhh1,
    const float* __restrict__ tWih0, const float* __restrict__ tWhh0,
    const float* __restrict__ tWih1, const float* __restrict__ tWhh1,
    const float* __restrict__ Wr, const float* __restrict__ Wt,
    half_t* __restrict__ w16) {
  const int idx = blockIdx.x * 256 + threadIdx.x;
  if (idx >= W_TOTAL) return;
  float v = 0.f;
  if (idx < OFF_W1) {
    int n = idx >> 6, kk = idx & 63;
    if (kk < 49) v = rWih0[n * 49 + kk];
  } else if (idx < OFF_W2) {
    int r = idx - OFF_W1; v = rWhh0[r];
  } else if (idx < OFF_W3) {
    int r = idx - OFF_W2; v = rWih1[r];
  } else if (idx < OFF_W4) {
    int r = idx - OFF_W3; v = rWhh1[r];
  } else if (idx < OFF_W5) {
    int r = idx - OFF_W4; int n = r >> 6, kk = r & 63;
    if (kk < 49) v = tWih0[n * 96 + kk];
  } else if (idx < OFF_W6) {
    int r = idx - OFF_W5; int n = r >> 6, kk = r & 63;
    if (kk < 47) v = tWih0[n * 96 + 49 + kk];
  } else if (idx < OFF_W7) {
    int r = idx - OFF_W6; v = tWhh0[r];
  } else if (idx < OFF_W8) {
    int r = idx - OFF_W7; v = tWih1[r];
  } else if (idx < OFF_W9) {
    int r = idx - OFF_W8; v = tWhh1[r];
  } else if (idx < OFF_W10) {
    int r = idx - OFF_W9; int n = r >> 9, kk = r & 511;
    if (n < 47) v = Wr[n * 512 + kk];
  } else {
    int r = idx - OFF_W10; int n = r >> 9, kk = r & 511;
    if (n < 2) v = Wt[n * 512 + kk];
  }
  w16[idx] = (half_t)v;
}

// fp32 x_r/x_t -> fp16 [t][128][64] (cols 0..46 = x_r, 47..48 = x_t, rest 0)
__global__ __launch_bounds__(256) void conv_x(const float* __restrict__ xr,
                                              const float* __restrict__ xt,
                                              half_t* __restrict__ x16) {
  const int idx = blockIdx.x * 256 + threadIdx.x;
  if (idx >= 512 * 128 * 64) return;
  const int kk = idx & 63;
  const int row = (idx >> 6) & 127;
  const int t = idx >> 13;
  float v = 0.f;
  if (kk < 47) v = xr[(row * 512 + t) * 47 + kk];
  else if (kk < 49) v = xt[(row * 512 + t) * 2 + (kk - 47)];
  x16[idx] = (half_t)v;
}

extern "C" void kernel_launch(void* const* d_in, const int* in_sizes, int n_in,
                              void* d_out, int out_size, void* d_ws,
                              size_t ws_size, hipStream_t stream) {
  const float* xr = (const float*)d_in[0];
  const float* xt = (const float*)d_in[1];
  const float* rWih0 = (const float*)d_in[2];
  const float* rWhh0 = (const float*)d_in[3];
  const float* r_b0 = (const float*)d_in[4];
  const float* rWih1 = (const float*)d_in[5];
  const float* rWhh1 = (const float*)d_in[6];
  const float* r_b1 = (const float*)d_in[7];
  const float* tWih0 = (const float*)d_in[8];
  const float* tWhh0 = (const float*)d_in[9];
  const float* t_b0 = (const float*)d_in[10];
  const float* tWih1 = (const float*)d_in[11];
  const float* tWhh1 = (const float*)d_in[12];
  const float* t_b1 = (const float*)d_in[13];
  const float* Wr = (const float*)d_in[14];
  const float* br = (const float*)d_in[15];
  const float* Wt = (const float*)d_in[16];
  const float* bt = (const float*)d_in[17];

  half_t* w16 = (half_t*)d_ws;
  float* cbase = (float*)((char*)d_ws + C_BYTE_OFF);
  unsigned* bar = (unsigned*)((char*)d_ws + BAR_BYTE_OFF);
  half_t* x16 = (half_t*)((char*)d_ws + X16_BYTE_OFF);
  float* out = (float*)d_out;
  int use_x16 = (ws_size >= WS_NEED_X16) ? 1 : 0;

  // zero h / ro / barrier state every call (deterministic)
  (void)hipMemsetAsync((char*)d_ws + STATE_BYTE_OFF, 0, STATE_BYTES, stream);

  conv_w<<<(W_TOTAL + 255) / 256, 256, 0, stream>>>(
      rWih0, rWhh0, rWih1, rWhh1, tWih0, tWhh0, tWih1, tWhh1, Wr, Wt, w16);
  if (use_x16)
    conv_x<<<(512 * 128 * 64) / 256, 256, 0, stream>>>(xr, xt, x16);

  adrnn_persist<<<NBLK, 256, 0, stream>>>(xr, xt, r_b0, r_b1, t_b0, t_b1, br,
                                          bt, w16, cbase, out, bar, x16,
                                          use_x16);
}